// Round 9
// baseline (574.486 us; speedup 1.0000x reference)
//
#include <hip/hip_runtime.h>

#define F_IN 500
#define HDIM 64
#define CDIM 10
#define KPAD 512           // K padded to 16 MFMA stages of 32
#define NSTAGE 16
#define H2LD 16            // padded h2s row stride (64 B lines)

typedef __attribute__((ext_vector_type(8))) short bf16x8;
typedef __attribute__((ext_vector_type(4))) float floatx4;

// RNE fp32 -> bf16 bits
__device__ inline unsigned short f2bf(float f) {
    unsigned int u = __float_as_uint(f);
    u += 0x7fffu + ((u >> 16) & 1u);
    return (unsigned short)(u >> 16);
}
__device__ inline float bflo(unsigned int u) { return __uint_as_float(u << 16); }
__device__ inline float bfhi(unsigned int u) { return __uint_as_float(u & 0xffff0000u); }

// ---------------------------------------------------------------------------
// Fused Stage 1: blocks [0, degB): in-degree histogram; the returned old
// value IS the edge's rank within its dst row -> erank.  Blocks [degB, ..):
// W1 split into trunc-bf16 hi + residual in MFMA B-fragment order.
// ---------------------------------------------------------------------------
__global__ __launch_bounds__(256) void prep_kernel(
        const int* __restrict__ dst, int E, int* __restrict__ deg,
        int* __restrict__ erank,
        const float* __restrict__ W1, unsigned short* __restrict__ whf,
        unsigned short* __restrict__ wlf, int degB) {
    int bid = blockIdx.x;
    if (bid < degB) {
        int e = bid * 256 + threadIdx.x;
        if (e < E) erank[e] = atomicAdd(&deg[dst[e]], 1);
    } else {
        int idx = (bid - degB) * 256 + threadIdx.x;  // over KPAD*HDIM
        if (idx >= KPAD * HDIM) return;
        int k = idx >> 6;
        int f = idx & 63;
        float w = (k < F_IN) ? W1[k * HDIM + f] : 0.f;
        unsigned int b = __float_as_uint(w);
        unsigned short hh = (unsigned short)(b >> 16);
        float wl = w - __uint_as_float(b & 0xffff0000u);
        unsigned short ll = (unsigned short)(__float_as_uint(wl) >> 16);
        int kb = k >> 5, q = (k >> 3) & 3, j = k & 7;
        int fb = f >> 4, fl = f & 15;
        int lane = (q << 4) | fl;
        size_t o = ((((size_t)kb * 4 + fb) * 64 + lane) << 3) | (size_t)j;
        whf[o] = hh;
        wlf[o] = ll;
    }
}

// ---------------------------------------------------------------------------
// Stage 2: per-block exclusive scan deg -> row_ptr partials; dis fused.
// Final row base = row_ptr[i] + blk_sum[i>>10]; consumers do the add.
// ---------------------------------------------------------------------------
__global__ void scan_block_kernel(const int* __restrict__ deg,
                                  int* __restrict__ row_ptr,
                                  int* __restrict__ blk_sum,
                                  float* __restrict__ dis, int Np1) {
    __shared__ int wsum[16];
    int i = blockIdx.x * 1024 + threadIdx.x;
    int v = (i < Np1 - 1) ? deg[i] : 0;
    if (i < Np1 - 1) dis[i] = rsqrtf((float)(v + 1));
    int lane = threadIdx.x & 63;
    int wid = threadIdx.x >> 6;
    int x = v;
#pragma unroll
    for (int off = 1; off < 64; off <<= 1) {
        int y = __shfl_up(x, off);
        if (lane >= off) x += y;
    }
    if (lane == 63) wsum[wid] = x;
    __syncthreads();
    if (threadIdx.x < 16) {
        int ws = wsum[threadIdx.x];
#pragma unroll
        for (int off = 1; off < 16; off <<= 1) {
            int y = __shfl_up(ws, off);
            if ((int)threadIdx.x >= off) ws += y;
        }
        wsum[threadIdx.x] = ws;
    }
    __syncthreads();
    int wp = (wid > 0) ? wsum[wid - 1] : 0;
    if (i < Np1) row_ptr[i] = wp + x - v;
    if (threadIdx.x == 1023) blk_sum[blockIdx.x] = wp + x;
}

__global__ void scan_top_kernel(int* __restrict__ blk_sum, int nb) {
    int carry = 0;
    for (int base = 0; base < nb; base += 64) {
        int i = base + (int)threadIdx.x;
        int v = (i < nb) ? blk_sum[i] : 0;
        int x = v;
#pragma unroll
        for (int off = 1; off < 64; off <<= 1) {
            int y = __shfl_up(x, off);
            if ((int)threadIdx.x >= off) x += y;
        }
        if (i < nb) blk_sum[i] = carry + x - v;
        carry += __shfl(x, 63);
    }
}

// ---------------------------------------------------------------------------
// Fused Stage 3+4, INTERLEAVED 1:4 (every 5th block is GEMM).  GEMM: one
// 16-node m-tile per wave, depth-3 software-pipelined x prefetch ring
// (statically indexed via unroll-3).  CSR path: atomic-free scatter using
// precomputed erank.
// ---------------------------------------------------------------------------
__global__ __launch_bounds__(256) void csr_gemm_kernel(
        // gemm args
        const float* __restrict__ x, const unsigned short* __restrict__ whf,
        const unsigned short* __restrict__ wlf, const float* __restrict__ dis,
        unsigned short* __restrict__ h1b, int N,
        // csr args
        const int* __restrict__ src, const int* __restrict__ dst,
        const int* __restrict__ erank,
        const int* __restrict__ row_ptr, const int* __restrict__ blk_sum,
        int* __restrict__ csr_src, int E,
        int gemmB) {
    const int bid = blockIdx.x;
    const int g5 = bid / 5;
    const bool isGemm = (bid % 5 == 0) && (g5 < gemmB);
    if (!isGemm) {
        // ----- CSR fill path (no atomics) -----
        int before = (bid + 4) / 5;          // gemm blocks preceding bid
        if (before > gemmB) before = gemmB;
        int cb = bid - before;
        int e = cb * 256 + threadIdx.x;
        if (e >= E) return;
        int d = dst[e];
        csr_src[row_ptr[d] + blk_sum[d >> 10] + erank[e]] = src[e];
        return;
    }
    // ----- GEMM path: one 16-node tile per wave -----
    const int lane = threadIdx.x & 63;
    const int wid = (g5 * 256 + threadIdx.x) >> 6;   // global gemm wave id
    const int n0 = wid * 16;
    if (n0 >= N) return;
    const int q = lane >> 4;
    const int fl = lane & 15;

    int r0 = n0 + fl;
    if (r0 >= N) r0 = N - 1;
    const float* xp = x + (size_t)r0 * F_IN + q * 8;

    floatx4 acc[4];
#pragma unroll
    for (int fb = 0; fb < 4; ++fb) acc[fb] = (floatx4){0.f, 0.f, 0.f, 0.f};

    const bf16x8* whv = (const bf16x8*)whf;
    const bf16x8* wlv = (const bf16x8*)wlf;

    // depth-3 prefetch ring over the 15 full stages (kb 0..14)
    float4 pa[3], pb[3];
#pragma unroll
    for (int s = 0; s < 3; ++s) {
        pa[s] = *(const float4*)(xp + s * 32);
        pb[s] = *(const float4*)(xp + s * 32 + 4);
    }

    for (int kbo = 0; kbo < 15; kbo += 3) {
#pragma unroll
        for (int s = 0; s < 3; ++s) {
            const int kb = kbo + s;
            float4 a = pa[s], b = pb[s];
            int kn = kb + 3;
            if (kn < 15) {  // issue the ring refill before consuming
                pa[s] = *(const float4*)(xp + kn * 32);
                pb[s] = *(const float4*)(xp + kn * 32 + 4);
            }
            float xv[8] = {a.x, a.y, a.z, a.w, b.x, b.y, b.z, b.w};
            bf16x8 xh, xl;
#pragma unroll
            for (int j = 0; j < 8; ++j) {
                unsigned int bb = __float_as_uint(xv[j]);
                xh[j] = (short)(bb >> 16);
                float res = xv[j] - __uint_as_float(bb & 0xffff0000u);
                xl[j] = (short)(__float_as_uint(res) >> 16);
            }
#pragma unroll
            for (int fb = 0; fb < 4; ++fb) {
                bf16x8 bh = whv[(size_t)(kb * 4 + fb) * 64 + lane];
                bf16x8 bl = wlv[(size_t)(kb * 4 + fb) * 64 + lane];
                acc[fb] = __builtin_amdgcn_mfma_f32_16x16x32_bf16(xh, bh, acc[fb], 0, 0, 0);
                acc[fb] = __builtin_amdgcn_mfma_f32_16x16x32_bf16(xl, bh, acc[fb], 0, 0, 0);
                acc[fb] = __builtin_amdgcn_mfma_f32_16x16x32_bf16(xh, bl, acc[fb], 0, 0, 0);
            }
        }
    }
    {   // tail stage kb = 15 (k 480..511, valid k < 500): guarded scalar loads
        const int kb = NSTAGE - 1;
        float xv[8];
#pragma unroll
        for (int j = 0; j < 8; ++j) {
            int kk = kb * 32 + q * 8 + j;
            xv[j] = (kk < F_IN) ? xp[kb * 32 + j] : 0.f;
        }
        bf16x8 xh, xl;
#pragma unroll
        for (int j = 0; j < 8; ++j) {
            unsigned int bb = __float_as_uint(xv[j]);
            xh[j] = (short)(bb >> 16);
            float res = xv[j] - __uint_as_float(bb & 0xffff0000u);
            xl[j] = (short)(__float_as_uint(res) >> 16);
        }
#pragma unroll
        for (int fb = 0; fb < 4; ++fb) {
            bf16x8 bh = whv[(size_t)(kb * 4 + fb) * 64 + lane];
            bf16x8 bl = wlv[(size_t)(kb * 4 + fb) * 64 + lane];
            acc[fb] = __builtin_amdgcn_mfma_f32_16x16x32_bf16(xh, bh, acc[fb], 0, 0, 0);
            acc[fb] = __builtin_amdgcn_mfma_f32_16x16x32_bf16(xl, bh, acc[fb], 0, 0, 0);
            acc[fb] = __builtin_amdgcn_mfma_f32_16x16x32_bf16(xh, bl, acc[fb], 0, 0, 0);
        }
    }
    // epilogue: D[m=q*4+r][n=fl]; node = n0 + q*4 + r, feat = fb*16 + fl
#pragma unroll
    for (int r = 0; r < 4; ++r) {
        int node = n0 + q * 4 + r;
        if (node < N) {
            float dn = dis[node];
#pragma unroll
            for (int fb = 0; fb < 4; ++fb) {
                h1b[(size_t)node * HDIM + fb * 16 + fl] =
                    f2bf(acc[fb][r] * dn);
            }
        }
    }
}

// ---------------------------------------------------------------------------
// Stage 5: gather layer 1.  h1b rows pre-scaled by dis[s] -> pure adds.
// Wave per node, half-wave per edge parity, 8 edges in flight per half.
// ---------------------------------------------------------------------------
__global__ __launch_bounds__(256) void gather1_kernel(
        const int* __restrict__ row_ptr, const int* __restrict__ blk_sum,
        const int* __restrict__ csr_src, const float* __restrict__ dis,
        const unsigned short* __restrict__ h1b,
        float* __restrict__ agg1, int N) {
    int nid = blockIdx.x * 4 + (threadIdx.x >> 6);
    if (nid >= N) return;
    int node = __builtin_amdgcn_readfirstlane(nid);
    int lane = threadIdx.x & 63;
    int half = lane >> 5;
    int c = lane & 31;  // features 2c, 2c+1
    int beg = row_ptr[node] + blk_sum[node >> 10];
    int end = row_ptr[node + 1] + blk_sum[(node + 1) >> 10];
    float dd = dis[node];
    float a0 = 0.f, a1 = 0.f;
    if (half == 0) {  // self-loop: row already holds h1*dis[node]
        unsigned int w = *reinterpret_cast<const unsigned int*>(
            h1b + (size_t)node * HDIM + 2 * c);
        a0 = bflo(w);
        a1 = bfhi(w);
    }
    int p = beg + half;
    for (; p + 14 < end; p += 16) {  // 8 edges in flight per half
        unsigned int wv[8];
#pragma unroll
        for (int i = 0; i < 8; ++i) {
            int s = csr_src[p + 2 * i];
            wv[i] = *reinterpret_cast<const unsigned int*>(
                h1b + (size_t)s * HDIM + 2 * c);
        }
#pragma unroll
        for (int i = 0; i < 8; ++i) {
            a0 += bflo(wv[i]);
            a1 += bfhi(wv[i]);
        }
    }
    for (; p < end; p += 2) {
        int s0 = csr_src[p];
        unsigned int w0 = *reinterpret_cast<const unsigned int*>(
            h1b + (size_t)s0 * HDIM + 2 * c);
        a0 += bflo(w0);
        a1 += bfhi(w0);
    }
    a0 += __shfl_xor(a0, 32);
    a1 += __shfl_xor(a1, 32);
    if (half == 0) {
        *reinterpret_cast<float2*>(agg1 + (size_t)node * HDIM + 2 * c) =
            make_float2(a0 * dd, a1 * dd);
    }
}

// ---------------------------------------------------------------------------
// Stage 6: layer 2 dense: t = relu(agg1+b1); h2s[n] = (t @ W2) * dis[n],
// row stride 16 (pad never read downstream).
// ---------------------------------------------------------------------------
__global__ void layer2_kernel(const float* __restrict__ agg1,
                              const float* __restrict__ b1,
                              const float* __restrict__ W2,
                              const float* __restrict__ dis,
                              float* __restrict__ h2s, int N) {
    int n = blockIdx.x * blockDim.x + threadIdx.x;
    if (n >= N) return;
    const float* ar = agg1 + (size_t)n * HDIM;
    float t[HDIM];
#pragma unroll
    for (int c = 0; c < HDIM; ++c) {
        float v = ar[c] + b1[c];
        t[c] = v > 0.f ? v : 0.f;
    }
    float dn = dis[n];
    float* h2r = h2s + (size_t)n * H2LD;
#pragma unroll
    for (int j = 0; j < CDIM; ++j) {
        float acc = 0.f;
#pragma unroll
        for (int c = 0; c < HDIM; ++c) acc = fmaf(t[c], W2[c * CDIM + j], acc);
        h2r[j] = acc * dn;
    }
}

// ---------------------------------------------------------------------------
// Stage 7: gather layer 2.  Wave per node, 4 groups x 16 lanes, 4 edges in
// flight per group; h2s rows 64-B aligned; shfl reduce; bias + self at end.
// ---------------------------------------------------------------------------
__global__ __launch_bounds__(256) void gather2_kernel(
        const int* __restrict__ row_ptr, const int* __restrict__ blk_sum,
        const int* __restrict__ csr_src, const float* __restrict__ dis,
        const float* __restrict__ h2s, const float* __restrict__ b2,
        float* __restrict__ out, int N) {
    int nid = blockIdx.x * 4 + (threadIdx.x >> 6);
    if (nid >= N) return;
    int node = __builtin_amdgcn_readfirstlane(nid);
    int lane = threadIdx.x & 63;
    int g = lane >> 4;
    int j = lane & 15;
    int beg = row_ptr[node] + blk_sum[node >> 10];
    int end = row_ptr[node + 1] + blk_sum[(node + 1) >> 10];
    float acc = 0.f;
    int p = beg + g;
    for (; p + 12 < end; p += 16) {  // 4 edges in flight per group
        int s0 = csr_src[p];
        int s1 = csr_src[p + 4];
        int s2 = csr_src[p + 8];
        int s3 = csr_src[p + 12];
        float v0 = (j < CDIM) ? h2s[(size_t)s0 * H2LD + j] : 0.f;
        float v1 = (j < CDIM) ? h2s[(size_t)s1 * H2LD + j] : 0.f;
        float v2 = (j < CDIM) ? h2s[(size_t)s2 * H2LD + j] : 0.f;
        float v3 = (j < CDIM) ? h2s[(size_t)s3 * H2LD + j] : 0.f;
        acc += (v0 + v1) + (v2 + v3);
    }
    for (; p < end; p += 4) {
        int s0 = csr_src[p];
        acc += (j < CDIM) ? h2s[(size_t)s0 * H2LD + j] : 0.f;
    }
    acc += __shfl_xor(acc, 16);
    acc += __shfl_xor(acc, 32);
    if (lane < CDIM) {
        float dd = dis[node];
        out[(size_t)node * CDIM + lane] =
            b2[lane] + dd * (acc + h2s[(size_t)node * H2LD + lane]);
    }
}

// ---------------------------------------------------------------------------
static inline char* align256(char* p) {
    return (char*)(((uintptr_t)p + 255) & ~(uintptr_t)255);
}

extern "C" void kernel_launch(void* const* d_in, const int* in_sizes, int n_in,
                              void* d_out, int out_size, void* d_ws,
                              size_t ws_size, hipStream_t stream) {
    const float* x  = (const float*)d_in[0];
    const int*   ei = (const int*)d_in[1];
    const float* W1 = (const float*)d_in[2];
    const float* b1 = (const float*)d_in[3];
    const float* W2 = (const float*)d_in[4];
    const float* b2 = (const float*)d_in[5];

    const int N = in_sizes[0] / F_IN;   // 100000
    const int E = in_sizes[1] / 2;      // 1600000
    const int* src = ei;
    const int* dst = ei + E;
    float* out = (float*)d_out;

    const int Np1 = N + 1;
    const int nscan_blocks = (Np1 + 1023) / 1024;

    // workspace layout (~38 MB), 256B-aligned chunks
    char* w = (char*)d_ws;
    int* deg = (int*)w;                  w = align256(w + (size_t)N * 4);  // zeroed
    char* zero_end = w;
    int* erank = (int*)w;                w = align256(w + (size_t)E * 4);
    float* dis = (float*)w;              w = align256(w + (size_t)N * 4);
    int* row_ptr = (int*)w;              w = align256(w + (size_t)(N + 4) * 4);
    int* blk_sum = (int*)w;              w = align256(w + (size_t)nscan_blocks * 4);
    int* csr_src = (int*)w;              w = align256(w + (size_t)E * 4);
    unsigned short* whf = (unsigned short*)w;  w = align256(w + (size_t)KPAD * HDIM * 2);
    unsigned short* wlf = (unsigned short*)w;  w = align256(w + (size_t)KPAD * HDIM * 2);
    unsigned short* h1b = (unsigned short*)w;  w = align256(w + (size_t)N * HDIM * 2);
    float* agg1 = (float*)w;             w = align256(w + (size_t)N * HDIM * 4);
    float* h2s = (float*)w;              w = align256(w + (size_t)N * H2LD * 4);

    hipMemsetAsync(deg, 0, (size_t)(zero_end - (char*)deg), stream);  // deg only

    const int degB = (E + 255) / 256;                    // 6250
    const int wprepB = (KPAD * HDIM + 255) / 256;        // 128
    prep_kernel<<<degB + wprepB, 256, 0, stream>>>(dst, E, deg, erank, W1, whf,
                                                   wlf, degB);
    scan_block_kernel<<<nscan_blocks, 1024, 0, stream>>>(deg, row_ptr, blk_sum,
                                                         dis, Np1);
    scan_top_kernel<<<1, 64, 0, stream>>>(blk_sum, nscan_blocks);
    {
        int gemmB = ((N + 15) / 16 + 3) / 4;             // 1563
        int csrB = (E + 255) / 256;                      // 6250
        csr_gemm_kernel<<<gemmB + csrB, 256, 0, stream>>>(
            x, whf, wlf, dis, h1b, N,
            src, dst, erank, row_ptr, blk_sum, csr_src, E, gemmB);
    }
    gather1_kernel<<<(N + 3) / 4, 256, 0, stream>>>(row_ptr, blk_sum, csr_src,
                                                    dis, h1b, agg1, N);
    layer2_kernel<<<(N + 255) / 256, 256, 0, stream>>>(agg1, b1, W2, dis, h2s,
                                                       N);
    gather2_kernel<<<(N + 3) / 4, 256, 0, stream>>>(row_ptr, blk_sum, csr_src,
                                                    dis, h2s, b2, out, N);
}

// Round 10
// 551.980 us; speedup vs baseline: 1.0408x; 1.0408x over previous
//
#include <hip/hip_runtime.h>

#define F_IN 500
#define HDIM 64
#define CDIM 10
#define KPAD 512           // K padded to 16 MFMA stages of 32
#define NSTAGE 16
#define H2LD 16            // padded h2s row stride (64 B lines)

typedef __attribute__((ext_vector_type(8))) short bf16x8;
typedef __attribute__((ext_vector_type(4))) float floatx4;

// RNE fp32 -> bf16 bits
__device__ inline unsigned short f2bf(float f) {
    unsigned int u = __float_as_uint(f);
    u += 0x7fffu + ((u >> 16) & 1u);
    return (unsigned short)(u >> 16);
}
__device__ inline float bflo(unsigned int u) { return __uint_as_float(u << 16); }
__device__ inline float bfhi(unsigned int u) { return __uint_as_float(u & 0xffff0000u); }

// ---------------------------------------------------------------------------
// Fused Stage 1: blocks [0, degB): in-degree histogram; the returned old
// value IS the edge's rank within its dst row -> erank.  Blocks [degB, ..):
// W1 split into trunc-bf16 hi + residual in MFMA B-fragment order.
// ---------------------------------------------------------------------------
__global__ __launch_bounds__(256) void prep_kernel(
        const int* __restrict__ dst, int E, int* __restrict__ deg,
        int* __restrict__ erank,
        const float* __restrict__ W1, unsigned short* __restrict__ whf,
        unsigned short* __restrict__ wlf, int degB) {
    int bid = blockIdx.x;
    if (bid < degB) {
        int e = bid * 256 + threadIdx.x;
        if (e < E) erank[e] = atomicAdd(&deg[dst[e]], 1);
    } else {
        int idx = (bid - degB) * 256 + threadIdx.x;  // over KPAD*HDIM
        if (idx >= KPAD * HDIM) return;
        int k = idx >> 6;
        int f = idx & 63;
        float w = (k < F_IN) ? W1[k * HDIM + f] : 0.f;
        unsigned int b = __float_as_uint(w);
        unsigned short hh = (unsigned short)(b >> 16);
        float wl = w - __uint_as_float(b & 0xffff0000u);
        unsigned short ll = (unsigned short)(__float_as_uint(wl) >> 16);
        int kb = k >> 5, q = (k >> 3) & 3, j = k & 7;
        int fb = f >> 4, fl = f & 15;
        int lane = (q << 4) | fl;
        size_t o = ((((size_t)kb * 4 + fb) * 64 + lane) << 3) | (size_t)j;
        whf[o] = hh;
        wlf[o] = ll;
    }
}

// ---------------------------------------------------------------------------
// Stage 2: per-block exclusive scan deg -> row_ptr partials; dis fused.
// Final row base = row_ptr[i] + blk_sum[i>>10]; consumers do the add.
// ---------------------------------------------------------------------------
__global__ void scan_block_kernel(const int* __restrict__ deg,
                                  int* __restrict__ row_ptr,
                                  int* __restrict__ blk_sum,
                                  float* __restrict__ dis, int Np1) {
    __shared__ int wsum[16];
    int i = blockIdx.x * 1024 + threadIdx.x;
    int v = (i < Np1 - 1) ? deg[i] : 0;
    if (i < Np1 - 1) dis[i] = rsqrtf((float)(v + 1));
    int lane = threadIdx.x & 63;
    int wid = threadIdx.x >> 6;
    int x = v;
#pragma unroll
    for (int off = 1; off < 64; off <<= 1) {
        int y = __shfl_up(x, off);
        if (lane >= off) x += y;
    }
    if (lane == 63) wsum[wid] = x;
    __syncthreads();
    if (threadIdx.x < 16) {
        int ws = wsum[threadIdx.x];
#pragma unroll
        for (int off = 1; off < 16; off <<= 1) {
            int y = __shfl_up(ws, off);
            if ((int)threadIdx.x >= off) ws += y;
        }
        wsum[threadIdx.x] = ws;
    }
    __syncthreads();
    int wp = (wid > 0) ? wsum[wid - 1] : 0;
    if (i < Np1) row_ptr[i] = wp + x - v;
    if (threadIdx.x == 1023) blk_sum[blockIdx.x] = wp + x;
}

__global__ void scan_top_kernel(int* __restrict__ blk_sum, int nb) {
    int carry = 0;
    for (int base = 0; base < nb; base += 64) {
        int i = base + (int)threadIdx.x;
        int v = (i < nb) ? blk_sum[i] : 0;
        int x = v;
#pragma unroll
        for (int off = 1; off < 64; off <<= 1) {
            int y = __shfl_up(x, off);
            if ((int)threadIdx.x >= off) x += y;
        }
        if (i < nb) blk_sum[i] = carry + x - v;
        carry += __shfl(x, 63);
    }
}

// ---------------------------------------------------------------------------
// Stage 3: CSR fill, atomic-free (rank precomputed in prep_kernel).
// ---------------------------------------------------------------------------
__global__ __launch_bounds__(256) void csr_fill_kernel(
        const int* __restrict__ src, const int* __restrict__ dst,
        const int* __restrict__ erank,
        const int* __restrict__ row_ptr, const int* __restrict__ blk_sum,
        int* __restrict__ csr_src, int E) {
    int e = blockIdx.x * 256 + threadIdx.x;
    if (e >= E) return;
    int d = dst[e];
    csr_src[row_ptr[d] + blk_sum[d >> 10] + erank[e]] = src[e];
}

// ---------------------------------------------------------------------------
// Stage 4: h1 = x @ W1 via bf16 MFMA, 3-pass split (xh*wh + xl*wh + xh*wl).
// One wave owns 32 nodes (2 m-tiles); depth-2 x prefetch; B-frags are
// pre-laid coalesced b128 loads.  Epilogue stores h1b = bf16(h1 * dis[n]).
// ---------------------------------------------------------------------------
__global__ __launch_bounds__(256) void gemm1_kernel(
        const float* __restrict__ x,
        const unsigned short* __restrict__ whf,
        const unsigned short* __restrict__ wlf,
        const float* __restrict__ dis,
        unsigned short* __restrict__ h1b, int N) {
    const int lane = threadIdx.x & 63;
    const int wid = (blockIdx.x * 256 + threadIdx.x) >> 6;
    const int n0 = wid * 32;
    if (n0 >= N) return;
    const int q = lane >> 4;
    const int fl = lane & 15;

    int r0 = n0 + fl;       if (r0 >= N) r0 = N - 1;
    int r1 = n0 + 16 + fl;  if (r1 >= N) r1 = N - 1;
    const float* xp0 = x + (size_t)r0 * F_IN + q * 8;
    const float* xp1 = x + (size_t)r1 * F_IN + q * 8;

    floatx4 acc[2][4];
#pragma unroll
    for (int t = 0; t < 2; ++t)
#pragma unroll
        for (int fb = 0; fb < 4; ++fb) acc[t][fb] = (floatx4){0.f, 0.f, 0.f, 0.f};

    const bf16x8* whv = (const bf16x8*)whf;
    const bf16x8* wlv = (const bf16x8*)wlf;

    // depth-2 pipeline: preload stage 0
    float4 na = *(const float4*)(xp0);
    float4 nb = *(const float4*)(xp0 + 4);
    float4 nc = *(const float4*)(xp1);
    float4 nd = *(const float4*)(xp1 + 4);

    for (int kb = 0; kb < NSTAGE - 1; ++kb) {
        float4 a = na, b = nb, c = nc, d = nd;
        if (kb + 1 < NSTAGE - 1) {  // issue next stage's loads before MFMA
            na = *(const float4*)(xp0 + (kb + 1) * 32);
            nb = *(const float4*)(xp0 + (kb + 1) * 32 + 4);
            nc = *(const float4*)(xp1 + (kb + 1) * 32);
            nd = *(const float4*)(xp1 + (kb + 1) * 32 + 4);
        }
        float xv0[8] = {a.x, a.y, a.z, a.w, b.x, b.y, b.z, b.w};
        float xv1[8] = {c.x, c.y, c.z, c.w, d.x, d.y, d.z, d.w};
        bf16x8 xh0, xl0, xh1, xl1;
#pragma unroll
        for (int j = 0; j < 8; ++j) {
            unsigned int b0 = __float_as_uint(xv0[j]);
            xh0[j] = (short)(b0 >> 16);
            float res0 = xv0[j] - __uint_as_float(b0 & 0xffff0000u);
            xl0[j] = (short)(__float_as_uint(res0) >> 16);
            unsigned int b1 = __float_as_uint(xv1[j]);
            xh1[j] = (short)(b1 >> 16);
            float res1 = xv1[j] - __uint_as_float(b1 & 0xffff0000u);
            xl1[j] = (short)(__float_as_uint(res1) >> 16);
        }
#pragma unroll
        for (int fb = 0; fb < 4; ++fb) {
            bf16x8 bh = whv[(size_t)(kb * 4 + fb) * 64 + lane];
            bf16x8 bl = wlv[(size_t)(kb * 4 + fb) * 64 + lane];
            acc[0][fb] = __builtin_amdgcn_mfma_f32_16x16x32_bf16(xh0, bh, acc[0][fb], 0, 0, 0);
            acc[0][fb] = __builtin_amdgcn_mfma_f32_16x16x32_bf16(xl0, bh, acc[0][fb], 0, 0, 0);
            acc[0][fb] = __builtin_amdgcn_mfma_f32_16x16x32_bf16(xh0, bl, acc[0][fb], 0, 0, 0);
            acc[1][fb] = __builtin_amdgcn_mfma_f32_16x16x32_bf16(xh1, bh, acc[1][fb], 0, 0, 0);
            acc[1][fb] = __builtin_amdgcn_mfma_f32_16x16x32_bf16(xl1, bh, acc[1][fb], 0, 0, 0);
            acc[1][fb] = __builtin_amdgcn_mfma_f32_16x16x32_bf16(xh1, bl, acc[1][fb], 0, 0, 0);
        }
    }
    {   // tail stage kb = NSTAGE-1 (k 480..511, valid k < 500), guarded loads
        const int kb = NSTAGE - 1;
        float xv0[8], xv1[8];
#pragma unroll
        for (int j = 0; j < 8; ++j) {
            int kk = kb * 32 + q * 8 + j;
            xv0[j] = (kk < F_IN) ? xp0[kb * 32 + j] : 0.f;
            xv1[j] = (kk < F_IN) ? xp1[kb * 32 + j] : 0.f;
        }
        bf16x8 xh0, xl0, xh1, xl1;
#pragma unroll
        for (int j = 0; j < 8; ++j) {
            unsigned int b0 = __float_as_uint(xv0[j]);
            xh0[j] = (short)(b0 >> 16);
            float res0 = xv0[j] - __uint_as_float(b0 & 0xffff0000u);
            xl0[j] = (short)(__float_as_uint(res0) >> 16);
            unsigned int b1 = __float_as_uint(xv1[j]);
            xh1[j] = (short)(b1 >> 16);
            float res1 = xv1[j] - __uint_as_float(b1 & 0xffff0000u);
            xl1[j] = (short)(__float_as_uint(res1) >> 16);
        }
#pragma unroll
        for (int fb = 0; fb < 4; ++fb) {
            bf16x8 bh = whv[(size_t)(kb * 4 + fb) * 64 + lane];
            bf16x8 bl = wlv[(size_t)(kb * 4 + fb) * 64 + lane];
            acc[0][fb] = __builtin_amdgcn_mfma_f32_16x16x32_bf16(xh0, bh, acc[0][fb], 0, 0, 0);
            acc[0][fb] = __builtin_amdgcn_mfma_f32_16x16x32_bf16(xl0, bh, acc[0][fb], 0, 0, 0);
            acc[0][fb] = __builtin_amdgcn_mfma_f32_16x16x32_bf16(xh0, bl, acc[0][fb], 0, 0, 0);
            acc[1][fb] = __builtin_amdgcn_mfma_f32_16x16x32_bf16(xh1, bh, acc[1][fb], 0, 0, 0);
            acc[1][fb] = __builtin_amdgcn_mfma_f32_16x16x32_bf16(xl1, bh, acc[1][fb], 0, 0, 0);
            acc[1][fb] = __builtin_amdgcn_mfma_f32_16x16x32_bf16(xh1, bl, acc[1][fb], 0, 0, 0);
        }
    }
#pragma unroll
    for (int t = 0; t < 2; ++t) {
#pragma unroll
        for (int r = 0; r < 4; ++r) {
            int node = n0 + t * 16 + q * 4 + r;
            if (node < N) {
                float dn = dis[node];
#pragma unroll
                for (int fb = 0; fb < 4; ++fb) {
                    h1b[(size_t)node * HDIM + fb * 16 + fl] =
                        f2bf(acc[t][fb][r] * dn);
                }
            }
        }
    }
}

// ---------------------------------------------------------------------------
// Stage 5: gather layer 1.  h1b rows pre-scaled by dis[s] -> pure adds.
// Wave per node, half-wave per edge parity, 8 edges in flight per half.
// ---------------------------------------------------------------------------
__global__ __launch_bounds__(256) void gather1_kernel(
        const int* __restrict__ row_ptr, const int* __restrict__ blk_sum,
        const int* __restrict__ csr_src, const float* __restrict__ dis,
        const unsigned short* __restrict__ h1b,
        float* __restrict__ agg1, int N) {
    int nid = blockIdx.x * 4 + (threadIdx.x >> 6);
    if (nid >= N) return;
    int node = __builtin_amdgcn_readfirstlane(nid);
    int lane = threadIdx.x & 63;
    int half = lane >> 5;
    int c = lane & 31;  // features 2c, 2c+1
    int beg = row_ptr[node] + blk_sum[node >> 10];
    int end = row_ptr[node + 1] + blk_sum[(node + 1) >> 10];
    float dd = dis[node];
    float a0 = 0.f, a1 = 0.f;
    if (half == 0) {  // self-loop: row already holds h1*dis[node]
        unsigned int w = *reinterpret_cast<const unsigned int*>(
            h1b + (size_t)node * HDIM + 2 * c);
        a0 = bflo(w);
        a1 = bfhi(w);
    }
    int p = beg + half;
    for (; p + 14 < end; p += 16) {  // 8 edges in flight per half
        unsigned int wv[8];
#pragma unroll
        for (int i = 0; i < 8; ++i) {
            int s = csr_src[p + 2 * i];
            wv[i] = *reinterpret_cast<const unsigned int*>(
                h1b + (size_t)s * HDIM + 2 * c);
        }
#pragma unroll
        for (int i = 0; i < 8; ++i) {
            a0 += bflo(wv[i]);
            a1 += bfhi(wv[i]);
        }
    }
    for (; p < end; p += 2) {
        int s0 = csr_src[p];
        unsigned int w0 = *reinterpret_cast<const unsigned int*>(
            h1b + (size_t)s0 * HDIM + 2 * c);
        a0 += bflo(w0);
        a1 += bfhi(w0);
    }
    a0 += __shfl_xor(a0, 32);
    a1 += __shfl_xor(a1, 32);
    if (half == 0) {
        *reinterpret_cast<float2*>(agg1 + (size_t)node * HDIM + 2 * c) =
            make_float2(a0 * dd, a1 * dd);
    }
}

// ---------------------------------------------------------------------------
// Stage 6: layer 2 dense: t = relu(agg1+b1); h2s[n] = (t @ W2) * dis[n],
// row stride 16 (pad never read downstream).
// ---------------------------------------------------------------------------
__global__ void layer2_kernel(const float* __restrict__ agg1,
                              const float* __restrict__ b1,
                              const float* __restrict__ W2,
                              const float* __restrict__ dis,
                              float* __restrict__ h2s, int N) {
    int n = blockIdx.x * blockDim.x + threadIdx.x;
    if (n >= N) return;
    const float* ar = agg1 + (size_t)n * HDIM;
    float t[HDIM];
#pragma unroll
    for (int c = 0; c < HDIM; ++c) {
        float v = ar[c] + b1[c];
        t[c] = v > 0.f ? v : 0.f;
    }
    float dn = dis[n];
    float* h2r = h2s + (size_t)n * H2LD;
#pragma unroll
    for (int j = 0; j < CDIM; ++j) {
        float acc = 0.f;
#pragma unroll
        for (int c = 0; c < HDIM; ++c) acc = fmaf(t[c], W2[c * CDIM + j], acc);
        h2r[j] = acc * dn;
    }
}

// ---------------------------------------------------------------------------
// Stage 7: gather layer 2.  Wave per node, 4 groups x 16 lanes, 4 edges in
// flight per group; h2s rows 64-B aligned; shfl reduce; bias + self at end.
// ---------------------------------------------------------------------------
__global__ __launch_bounds__(256) void gather2_kernel(
        const int* __restrict__ row_ptr, const int* __restrict__ blk_sum,
        const int* __restrict__ csr_src, const float* __restrict__ dis,
        const float* __restrict__ h2s, const float* __restrict__ b2,
        float* __restrict__ out, int N) {
    int nid = blockIdx.x * 4 + (threadIdx.x >> 6);
    if (nid >= N) return;
    int node = __builtin_amdgcn_readfirstlane(nid);
    int lane = threadIdx.x & 63;
    int g = lane >> 4;
    int j = lane & 15;
    int beg = row_ptr[node] + blk_sum[node >> 10];
    int end = row_ptr[node + 1] + blk_sum[(node + 1) >> 10];
    float acc = 0.f;
    int p = beg + g;
    for (; p + 12 < end; p += 16) {  // 4 edges in flight per group
        int s0 = csr_src[p];
        int s1 = csr_src[p + 4];
        int s2 = csr_src[p + 8];
        int s3 = csr_src[p + 12];
        float v0 = (j < CDIM) ? h2s[(size_t)s0 * H2LD + j] : 0.f;
        float v1 = (j < CDIM) ? h2s[(size_t)s1 * H2LD + j] : 0.f;
        float v2 = (j < CDIM) ? h2s[(size_t)s2 * H2LD + j] : 0.f;
        float v3 = (j < CDIM) ? h2s[(size_t)s3 * H2LD + j] : 0.f;
        acc += (v0 + v1) + (v2 + v3);
    }
    for (; p < end; p += 4) {
        int s0 = csr_src[p];
        acc += (j < CDIM) ? h2s[(size_t)s0 * H2LD + j] : 0.f;
    }
    acc += __shfl_xor(acc, 16);
    acc += __shfl_xor(acc, 32);
    if (lane < CDIM) {
        float dd = dis[node];
        out[(size_t)node * CDIM + lane] =
            b2[lane] + dd * (acc + h2s[(size_t)node * H2LD + lane]);
    }
}

// ---------------------------------------------------------------------------
static inline char* align256(char* p) {
    return (char*)(((uintptr_t)p + 255) & ~(uintptr_t)255);
}

extern "C" void kernel_launch(void* const* d_in, const int* in_sizes, int n_in,
                              void* d_out, int out_size, void* d_ws,
                              size_t ws_size, hipStream_t stream) {
    const float* x  = (const float*)d_in[0];
    const int*   ei = (const int*)d_in[1];
    const float* W1 = (const float*)d_in[2];
    const float* b1 = (const float*)d_in[3];
    const float* W2 = (const float*)d_in[4];
    const float* b2 = (const float*)d_in[5];

    const int N = in_sizes[0] / F_IN;   // 100000
    const int E = in_sizes[1] / 2;      // 1600000
    const int* src = ei;
    const int* dst = ei + E;
    float* out = (float*)d_out;

    const int Np1 = N + 1;
    const int nscan_blocks = (Np1 + 1023) / 1024;

    // workspace layout (~38 MB), 256B-aligned chunks
    char* w = (char*)d_ws;
    int* deg = (int*)w;                  w = align256(w + (size_t)N * 4);  // zeroed
    char* zero_end = w;
    int* erank = (int*)w;                w = align256(w + (size_t)E * 4);
    float* dis = (float*)w;              w = align256(w + (size_t)N * 4);
    int* row_ptr = (int*)w;              w = align256(w + (size_t)(N + 4) * 4);
    int* blk_sum = (int*)w;              w = align256(w + (size_t)nscan_blocks * 4);
    int* csr_src = (int*)w;              w = align256(w + (size_t)E * 4);
    unsigned short* whf = (unsigned short*)w;  w = align256(w + (size_t)KPAD * HDIM * 2);
    unsigned short* wlf = (unsigned short*)w;  w = align256(w + (size_t)KPAD * HDIM * 2);
    unsigned short* h1b = (unsigned short*)w;  w = align256(w + (size_t)N * HDIM * 2);
    float* agg1 = (float*)w;             w = align256(w + (size_t)N * HDIM * 4);
    float* h2s = (float*)w;              w = align256(w + (size_t)N * H2LD * 4);

    hipMemsetAsync(deg, 0, (size_t)(zero_end - (char*)deg), stream);  // deg only

    const int degB = (E + 255) / 256;                    // 6250
    const int wprepB = (KPAD * HDIM + 255) / 256;        // 128
    prep_kernel<<<degB + wprepB, 256, 0, stream>>>(dst, E, deg, erank, W1, whf,
                                                   wlf, degB);
    scan_block_kernel<<<nscan_blocks, 1024, 0, stream>>>(deg, row_ptr, blk_sum,
                                                         dis, Np1);
    scan_top_kernel<<<1, 64, 0, stream>>>(blk_sum, nscan_blocks);
    {
        int gemmB = ((N + 31) / 32 + 3) / 4;             // 782
        gemm1_kernel<<<gemmB, 256, 0, stream>>>(x, whf, wlf, dis, h1b, N);
    }
    csr_fill_kernel<<<(E + 255) / 256, 256, 0, stream>>>(src, dst, erank,
                                                         row_ptr, blk_sum,
                                                         csr_src, E);
    gather1_kernel<<<(N + 3) / 4, 256, 0, stream>>>(row_ptr, blk_sum, csr_src,
                                                    dis, h1b, agg1, N);
    layer2_kernel<<<(N + 255) / 256, 256, 0, stream>>>(agg1, b1, W2, dis, h2s,
                                                       N);
    gather2_kernel<<<(N + 3) / 4, 256, 0, stream>>>(row_ptr, blk_sum, csr_src,
                                                    dis, h2s, b2, out, N);
}